// Round 1
// baseline (1997.316 us; speedup 1.0000x reference)
//
#include <hip/hip_runtime.h>

#define NB 8
#define N_PER 4096
#define N_SAMPLE 1024
#define KNN 64
#define CIN 64
#define HD 128
#define R2F 0.04f
#define LIST_CAP 384

// ---------------- FPS: one block per cloud, exact f32 match to reference ----
__global__ __launch_bounds__(256) void fps_kernel(const float* __restrict__ pos,
                                                  int* __restrict__ idx_out,
                                                  float* __restrict__ pos_out,
                                                  float* __restrict__ batch_out) {
    __shared__ float px[N_PER], py[N_PER], pz[N_PER];
    __shared__ float pval[2][4];
    __shared__ int   pidx[2][4];
    const int t = threadIdx.x;
    const int b = blockIdx.x;
    const float* posb = pos + (size_t)b * N_PER * 3;
    for (int i = t; i < N_PER; i += 256) {
        px[i] = posb[i * 3 + 0];
        py[i] = posb[i * 3 + 1];
        pz[i] = posb[i * 3 + 2];
    }
    // batch_out as float values
    for (int i = t; i < N_SAMPLE; i += 256) batch_out[b * N_SAMPLE + i] = (float)b;
    __syncthreads();

    float mind[16];
#pragma unroll
    for (int k = 0; k < 16; ++k) mind[k] = 1e10f;
    int last = 0;
    if (t == 0) {
        idx_out[b * N_SAMPLE] = b * N_PER;  // global index of point 0
        pos_out[(size_t)(b * N_SAMPLE) * 3 + 0] = px[0];
        pos_out[(size_t)(b * N_SAMPLE) * 3 + 1] = py[0];
        pos_out[(size_t)(b * N_SAMPLE) * 3 + 2] = pz[0];
    }

    for (int s = 1; s < N_SAMPLE; ++s) {
        const float lx = px[last], ly = py[last], lz = pz[last];
        float bv = -1.0f;
        int bi = 0x7fffffff;
#pragma unroll
        for (int k = 0; k < 16; ++k) {
            const int p = t + (k << 8);
            const float dx = px[p] - lx;
            const float dy = py[p] - ly;
            const float dz = pz[p] - lz;
            // exact f32: (dx*dx + dy*dy) + dz*dz, no FMA contraction
            const float d = __fadd_rn(__fadd_rn(__fmul_rn(dx, dx), __fmul_rn(dy, dy)),
                                      __fmul_rn(dz, dz));
            const float m = fminf(mind[k], d);
            mind[k] = m;
            if (m > bv) { bv = m; bi = p; }  // strict > keeps lowest index (k ascending)
        }
        // wave reduce (64 lanes), first-max tie-break on lower index
#pragma unroll
        for (int off = 32; off > 0; off >>= 1) {
            const float ov = __shfl_down(bv, off);
            const int   oi = __shfl_down(bi, off);
            if (ov > bv || (ov == bv && oi < bi)) { bv = ov; bi = oi; }
        }
        const int wv = t >> 6;
        const int par = s & 1;
        if ((t & 63) == 0) { pval[par][wv] = bv; pidx[par][wv] = bi; }
        __syncthreads();
        float fv = pval[par][0];
        int fi = pidx[par][0];
#pragma unroll
        for (int w = 1; w < 4; ++w) {
            const float ov = pval[par][w];
            const int   oi = pidx[par][w];
            if (ov > fv || (ov == fv && oi < fi)) { fv = ov; fi = oi; }
        }
        last = fi;
        if (t == 0) {
            idx_out[b * N_SAMPLE + s] = b * N_PER + fi;
            pos_out[(size_t)(b * N_SAMPLE + s) * 3 + 0] = px[fi];
            pos_out[(size_t)(b * N_SAMPLE + s) * 3 + 1] = py[fi];
            pos_out[(size_t)(b * N_SAMPLE + s) * 3 + 2] = pz[fi];
        }
        // ping-pong partial buffers make a trailing barrier unnecessary
    }
}

// ---------------- g = x@W1[:64] + pos@W1[64:67] + b1  (per-point, no pair dep)
__global__ __launch_bounds__(256) void g_kernel(const float* __restrict__ x,
                                                const float* __restrict__ pos,
                                                const float* __restrict__ W1,
                                                const float* __restrict__ b1,
                                                float* __restrict__ g) {
    __shared__ float xs[2 * CIN];
    __shared__ float ps[6];
    const int t = threadIdx.x;
    const int n0 = blockIdx.x * 2;
    if (t < 2 * CIN) xs[t] = x[(size_t)n0 * CIN + t];
    if (t < 6) ps[t] = pos[(size_t)n0 * 3 + t];
    __syncthreads();
    const int lp = t >> 7;
    const int h = t & 127;
    float acc = b1[h];
    const float* xv = xs + lp * CIN;
#pragma unroll 8
    for (int c = 0; c < CIN; ++c) acc += xv[c] * W1[c * HD + h];
    const float* pv = ps + lp * 3;
#pragma unroll
    for (int d = 0; d < 3; ++d) acc += pv[d] * W1[(CIN + d) * HD + h];
    g[(size_t)(n0 + lp) * HD + h] = acc;
}

// ---------------- main: ball-query select + h1 + layer2 GEMM + masked max ---
__global__ __launch_bounds__(256) void main_kernel(const float* __restrict__ pos,
                                                   const float* __restrict__ W1,
                                                   const float* __restrict__ W2,
                                                   const float* __restrict__ b2,
                                                   const float* __restrict__ g,
                                                   const int* __restrict__ idx_in,
                                                   float* __restrict__ x_out) {
    __shared__ float h1[KNN][HD + 4];     // pad 132 to break 512B stride
    __shared__ float W2c[32 * HD];        // 32 rows of W2
    __shared__ unsigned long long keys[LIST_CAP];
    __shared__ int sel[KNN];
    __shared__ float pcW[HD];
    __shared__ float cp[3];
    __shared__ int cnt;
    __shared__ float partial[4][16][8];

    const int t = threadIdx.x;
    const int s = blockIdx.x;
    const int b = s >> 10;
    const int gci = idx_in[s];
    if (t < 3) cp[t] = pos[(size_t)gci * 3 + t];
    if (t == 0) cnt = 0;
    __syncthreads();

    if (t < HD) {
        pcW[t] = cp[0] * W1[CIN * HD + t] + cp[1] * W1[(CIN + 1) * HD + t] +
                 cp[2] * W1[(CIN + 2) * HD + t];
    }

    // filter points within radius into LDS list
    const float cx = cp[0], cy = cp[1], cz = cp[2];
    const size_t base = (size_t)b * N_PER;
#pragma unroll
    for (int k = 0; k < 16; ++k) {
        const int p = t + (k << 8);
        const float* pp = pos + (base + p) * 3;
        const float dx = pp[0] - cx;
        const float dy = pp[1] - cy;
        const float dz = pp[2] - cz;
        const float d2 = __fadd_rn(__fadd_rn(__fmul_rn(dx, dx), __fmul_rn(dy, dy)),
                                   __fmul_rn(dz, dz));
        if (d2 <= R2F) {
            const int slot = atomicAdd(&cnt, 1);
            if (slot < LIST_CAP)
                keys[slot] = ((unsigned long long)__float_as_uint(d2) << 32) | (unsigned)p;
        }
    }
    __syncthreads();
    const int C = min(cnt, LIST_CAP);
    const int M = min(C, KNN);

    // exact top-K selection by rank of (d2, idx) key  (O(C^2), C ~ 137)
    for (int e = t; e < C; e += 256) {
        const unsigned long long ke = keys[e];
        int rank = 0;
        for (int q = 0; q < C; ++q) rank += (keys[q] < ke) ? 1 : 0;
        if (rank < KNN) sel[rank] = (int)(ke & 0xFFFFFFFFull);
    }
    __syncthreads();

    // h1[m][h] = relu(g[j_m][h] - pcW[h])
    for (int lin = t; lin < KNN * HD; lin += 256) {
        const int m = lin >> 7;
        const int h = lin & 127;
        float v = 0.0f;
        if (m < M) v = fmaxf(g[(base + sel[m]) * HD + h] - pcW[h], 0.0f);
        h1[m][h] = v;
    }
    __syncthreads();

    // layer 2: [64x128] @ [128x128], thread tile 4m x 8o
    const int og = t & 15;
    const int mg = t >> 4;
    float acc[4][8];
#pragma unroll
    for (int i = 0; i < 4; ++i)
#pragma unroll
        for (int j = 0; j < 8; ++j) acc[i][j] = 0.0f;

    for (int h0 = 0; h0 < HD; h0 += 32) {
        for (int lin = t * 4; lin < 32 * HD; lin += 1024) {
            *(float4*)(W2c + lin) = *(const float4*)(W2 + (size_t)h0 * HD + lin);
        }
        __syncthreads();
#pragma unroll
        for (int hh = 0; hh < 32; hh += 4) {
            float a4[4][4];
#pragma unroll
            for (int i = 0; i < 4; ++i) {
                const float4 v = *(const float4*)(&h1[mg * 4 + i][h0 + hh]);
                a4[i][0] = v.x; a4[i][1] = v.y; a4[i][2] = v.z; a4[i][3] = v.w;
            }
#pragma unroll
            for (int hp = 0; hp < 4; ++hp) {
                const float4 w0 = *(const float4*)(W2c + (hh + hp) * HD + og * 8);
                const float4 w1 = *(const float4*)(W2c + (hh + hp) * HD + og * 8 + 4);
                const float w[8] = {w0.x, w0.y, w0.z, w0.w, w1.x, w1.y, w1.z, w1.w};
#pragma unroll
                for (int i = 0; i < 4; ++i)
#pragma unroll
                    for (int j = 0; j < 8; ++j) acc[i][j] += a4[i][hp] * w[j];
            }
        }
        __syncthreads();
    }

    // + b2, relu, mask invalid m, max over m
    const float4 bA = *(const float4*)(b2 + og * 8);
    const float4 bB = *(const float4*)(b2 + og * 8 + 4);
    const float b2r[8] = {bA.x, bA.y, bA.z, bA.w, bB.x, bB.y, bB.z, bB.w};
    float mx[8];
#pragma unroll
    for (int j = 0; j < 8; ++j) mx[j] = -1e9f;
#pragma unroll
    for (int i = 0; i < 4; ++i) {
        const int m = mg * 4 + i;
        if (m < M) {
#pragma unroll
            for (int j = 0; j < 8; ++j) {
                const float v = fmaxf(acc[i][j] + b2r[j], 0.0f);
                mx[j] = fmaxf(mx[j], v);
            }
        }
    }
#pragma unroll
    for (int j = 0; j < 8; ++j) {
        mx[j] = fmaxf(mx[j], __shfl_xor(mx[j], 16));
        mx[j] = fmaxf(mx[j], __shfl_xor(mx[j], 32));
    }
    const int wv = t >> 6;
    if ((t & 63) < 16) {
#pragma unroll
        for (int j = 0; j < 8; ++j) partial[wv][t & 15][j] = mx[j];
    }
    __syncthreads();
    if (t < HD) {
        const int ogr = t >> 3, j = t & 7;
        const float v = fmaxf(fmaxf(partial[0][ogr][j], partial[1][ogr][j]),
                              fmaxf(partial[2][ogr][j], partial[3][ogr][j]));
        x_out[(size_t)s * HD + t] = v;
    }
}

extern "C" void kernel_launch(void* const* d_in, const int* in_sizes, int n_in,
                              void* d_out, int out_size, void* d_ws, size_t ws_size,
                              hipStream_t stream) {
    const float* x   = (const float*)d_in[0];
    const float* pos = (const float*)d_in[1];
    const float* W1  = (const float*)d_in[2];
    const float* b1  = (const float*)d_in[3];
    const float* W2  = (const float*)d_in[4];
    const float* b2  = (const float*)d_in[5];
    // d_in[6] = batch (uniform, unused)

    float* out = (float*)d_out;
    float* x_out     = out;                                  // [8192,128]
    float* pos_out   = out + (size_t)NB * N_SAMPLE * HD;     // [8192,3]
    float* batch_out = pos_out + (size_t)NB * N_SAMPLE * 3;  // [8192]

    int*   idx_ws = (int*)d_ws;                              // 8192 ints
    float* g      = (float*)((char*)d_ws + 65536);           // [32768,128] f32 = 16MB

    fps_kernel<<<NB, 256, 0, stream>>>(pos, idx_ws, pos_out, batch_out);
    g_kernel<<<(NB * N_PER) / 2, 256, 0, stream>>>(x, pos, W1, b1, g);
    main_kernel<<<NB * N_SAMPLE, 256, 0, stream>>>(pos, W1, W2, b2, g, idx_ws, x_out);
}

// Round 2
// 1202.393 us; speedup vs baseline: 1.6611x; 1.6611x over previous
//
#include <hip/hip_runtime.h>

#define NB 8
#define N_PER 4096
#define N_SAMPLE 1024
#define KNN 64
#define CIN 64
#define HD 128
#define R2F 0.04f
#define LIST_CAP 384

// ---- combined FPS (blocks 0..7) + g precompute (blocks 8..) ----------------
// g = x@W1[:64] + pos@W1[64:67] + b1  (per-point part of layer 1)
__global__ __launch_bounds__(256) void fps_g_kernel(const float* __restrict__ pos,
                                                    const float* __restrict__ x,
                                                    const float* __restrict__ W1,
                                                    const float* __restrict__ b1,
                                                    float* __restrict__ g,
                                                    int* __restrict__ idx_out,
                                                    float* __restrict__ pos_out,
                                                    float* __restrict__ batch_out) {
    __shared__ float px[N_PER], py[N_PER], pz[N_PER];
    __shared__ unsigned long long pkey[2][4];
    const int t = threadIdx.x;

    if (blockIdx.x >= NB) {
        // ---------------- g part: 2 points per block ----------------
        const int n0 = (int)(blockIdx.x - NB) * 2;
        if (t < 2 * CIN) px[t] = x[(size_t)n0 * CIN + t];
        if (t < 6) py[t] = pos[(size_t)n0 * 3 + t];
        __syncthreads();
        const int lp = t >> 7;
        const int h = t & 127;
        float acc = b1[h];
        const float* xv = px + lp * CIN;
#pragma unroll 8
        for (int c = 0; c < CIN; ++c) acc += xv[c] * W1[c * HD + h];
        const float* pv = py + lp * 3;
#pragma unroll
        for (int d = 0; d < 3; ++d) acc += pv[d] * W1[(CIN + d) * HD + h];
        g[(size_t)(n0 + lp) * HD + h] = acc;
        return;
    }

    // ---------------- FPS part: one block per cloud ----------------
    const int b = blockIdx.x;
    const float* posb = pos + (size_t)b * N_PER * 3;
    for (int i = t; i < N_PER; i += 256) {
        px[i] = posb[i * 3 + 0];
        py[i] = posb[i * 3 + 1];
        pz[i] = posb[i * 3 + 2];
    }
    for (int i = t; i < N_SAMPLE; i += 256) batch_out[b * N_SAMPLE + i] = (float)b;
    __syncthreads();

    // registers hold this thread's 16 points (LDS kept for broadcast of `last`)
    float rx[16], ry[16], rz[16], mind[16];
#pragma unroll
    for (int k = 0; k < 16; ++k) {
        const int p = t + (k << 8);
        rx[k] = px[p]; ry[k] = py[p]; rz[k] = pz[p];
        mind[k] = 1e10f;
    }
    int last = 0;
    if (t == 0) {
        idx_out[b * N_SAMPLE] = b * N_PER;
        pos_out[(size_t)(b * N_SAMPLE) * 3 + 0] = px[0];
        pos_out[(size_t)(b * N_SAMPLE) * 3 + 1] = py[0];
        pos_out[(size_t)(b * N_SAMPLE) * 3 + 2] = pz[0];
    }

    for (int s = 1; s < N_SAMPLE; ++s) {
        const float lx = px[last], ly = py[last], lz = pz[last];
        float bv = -1.0f;
        int bi = 0x7fffffff;
#pragma unroll
        for (int k = 0; k < 16; ++k) {
            const float dx = rx[k] - lx;
            const float dy = ry[k] - ly;
            const float dz = rz[k] - lz;
            // exact f32 left-to-right: (dx*dx + dy*dy) + dz*dz, no FMA contraction
            const float d = __fadd_rn(__fadd_rn(__fmul_rn(dx, dx), __fmul_rn(dy, dy)),
                                      __fmul_rn(dz, dz));
            const float m = fminf(mind[k], d);
            mind[k] = m;
            if (m > bv) { bv = m; bi = t + (k << 8); }  // strict > keeps lowest index
        }
        // pack (dist, ~idx): u64 max == (max dist, ties -> smaller idx). bv >= 0 so
        // the float bit pattern is monotonic under unsigned compare.
        unsigned long long key =
            ((unsigned long long)__float_as_uint(bv) << 32) | (unsigned)(~bi);
#pragma unroll
        for (int off = 32; off > 0; off >>= 1) {
            const unsigned long long ok = __shfl_down(key, off);
            key = (ok > key) ? ok : key;
        }
        const int par = s & 1;
        if ((t & 63) == 0) pkey[par][t >> 6] = key;
        __syncthreads();
        unsigned long long fk = pkey[par][0];
#pragma unroll
        for (int w = 1; w < 4; ++w) {
            const unsigned long long ok = pkey[par][w];
            fk = (ok > fk) ? ok : fk;
        }
        last = (int)(~(unsigned)fk);
        if (t == 0) {
            idx_out[b * N_SAMPLE + s] = b * N_PER + last;
            pos_out[(size_t)(b * N_SAMPLE + s) * 3 + 0] = px[last];
            pos_out[(size_t)(b * N_SAMPLE + s) * 3 + 1] = py[last];
            pos_out[(size_t)(b * N_SAMPLE + s) * 3 + 2] = pz[last];
        }
        // parity ping-pong on pkey avoids a trailing barrier
    }
}

// ---- main: ball-query select + h1 + layer2 GEMM + masked max ---------------
__global__ __launch_bounds__(256) void main_kernel(const float* __restrict__ pos,
                                                   const float* __restrict__ W1,
                                                   const float* __restrict__ W2,
                                                   const float* __restrict__ b2,
                                                   const float* __restrict__ g,
                                                   const int* __restrict__ idx_in,
                                                   float* __restrict__ x_out) {
    __shared__ float h1[KNN][HD + 4];  // stride 132; readers use m = mg+16i (2-way max)
    __shared__ unsigned long long keys[LIST_CAP];
    __shared__ int sel[KNN];
    __shared__ float pcW[HD];
    __shared__ float cp[3];
    __shared__ int cnt;
    __shared__ float partial[4][16][8];

    const int t = threadIdx.x;
    const int s = blockIdx.x;
    const int b = s >> 10;
    const int gci = idx_in[s];
    if (t < 3) cp[t] = pos[(size_t)gci * 3 + t];
    if (t == 0) cnt = 0;
    __syncthreads();

    if (t < HD) {
        pcW[t] = cp[0] * W1[CIN * HD + t] + cp[1] * W1[(CIN + 1) * HD + t] +
                 cp[2] * W1[(CIN + 2) * HD + t];
    }

    const float cx = cp[0], cy = cp[1], cz = cp[2];
    const size_t base = (size_t)b * N_PER;
#pragma unroll
    for (int k = 0; k < 16; ++k) {
        const int p = t + (k << 8);
        const float* pp = pos + (base + p) * 3;
        const float dx = pp[0] - cx;
        const float dy = pp[1] - cy;
        const float dz = pp[2] - cz;
        const float d2 = __fadd_rn(__fadd_rn(__fmul_rn(dx, dx), __fmul_rn(dy, dy)),
                                   __fmul_rn(dz, dz));
        if (d2 <= R2F) {
            const int slot = atomicAdd(&cnt, 1);
            if (slot < LIST_CAP)
                keys[slot] = ((unsigned long long)__float_as_uint(d2) << 32) | (unsigned)p;
        }
    }
    __syncthreads();
    const int C = min(cnt, LIST_CAP);
    const int M = min(C, KNN);

    // exact top-K by rank of (d2, idx) key (matches lax.top_k tie semantics)
    for (int e = t; e < C; e += 256) {
        const unsigned long long ke = keys[e];
        int rank = 0;
        for (int q = 0; q < C; ++q) rank += (keys[q] < ke) ? 1 : 0;
        if (rank < KNN) sel[rank] = (int)(ke & 0xFFFFFFFFull);
    }
    __syncthreads();

    // h1[m][h] = relu(g[j_m][h] - pcW[h]); zero for invalid rows
    for (int lin = t; lin < KNN * HD; lin += 256) {
        const int m = lin >> 7;
        const int h = lin & 127;
        float v = 0.0f;
        if (m < M) v = fmaxf(g[(base + sel[m]) * HD + h] - pcW[h], 0.0f);
        h1[m][h] = v;
    }
    __syncthreads();

    // layer 2: [64x128] @ [128x128]; thread tile 4m x 8o, rows m = mg + 16*i
    // W2 read directly from global (L1/L2 broadcast) -> no staging barriers
    const int og = t & 15;
    const int mg = t >> 4;
    float acc[4][8];
#pragma unroll
    for (int i = 0; i < 4; ++i)
#pragma unroll
        for (int j = 0; j < 8; ++j) acc[i][j] = 0.0f;

    for (int h0 = 0; h0 < HD; h0 += 16) {
#pragma unroll
        for (int hh = 0; hh < 16; hh += 4) {
            float a4[4][4];
#pragma unroll
            for (int i = 0; i < 4; ++i) {
                const float4 v = *(const float4*)(&h1[mg + 16 * i][h0 + hh]);
                a4[i][0] = v.x; a4[i][1] = v.y; a4[i][2] = v.z; a4[i][3] = v.w;
            }
#pragma unroll
            for (int hp = 0; hp < 4; ++hp) {
                const int row = h0 + hh + hp;
                const float4 w0 = *(const float4*)(W2 + (size_t)row * HD + og * 8);
                const float4 w1 = *(const float4*)(W2 + (size_t)row * HD + og * 8 + 4);
                const float w[8] = {w0.x, w0.y, w0.z, w0.w, w1.x, w1.y, w1.z, w1.w};
#pragma unroll
                for (int i = 0; i < 4; ++i)
#pragma unroll
                    for (int j = 0; j < 8; ++j) acc[i][j] += a4[i][hp] * w[j];
            }
        }
    }

    // + b2, relu, mask invalid rows, max over m
    const float4 bA = *(const float4*)(b2 + og * 8);
    const float4 bB = *(const float4*)(b2 + og * 8 + 4);
    const float b2r[8] = {bA.x, bA.y, bA.z, bA.w, bB.x, bB.y, bB.z, bB.w};
    float mx[8];
#pragma unroll
    for (int j = 0; j < 8; ++j) mx[j] = -1e9f;
#pragma unroll
    for (int i = 0; i < 4; ++i) {
        const int m = mg + 16 * i;
        if (m < M) {
#pragma unroll
            for (int j = 0; j < 8; ++j) {
                const float v = fmaxf(acc[i][j] + b2r[j], 0.0f);
                mx[j] = fmaxf(mx[j], v);
            }
        }
    }
#pragma unroll
    for (int j = 0; j < 8; ++j) {
        mx[j] = fmaxf(mx[j], __shfl_xor(mx[j], 16));
        mx[j] = fmaxf(mx[j], __shfl_xor(mx[j], 32));
    }
    const int wv = t >> 6;
    if ((t & 63) < 16) {
#pragma unroll
        for (int j = 0; j < 8; ++j) partial[wv][t & 15][j] = mx[j];
    }
    __syncthreads();
    if (t < HD) {
        const int ogr = t >> 3, j = t & 7;
        const float v = fmaxf(fmaxf(partial[0][ogr][j], partial[1][ogr][j]),
                              fmaxf(partial[2][ogr][j], partial[3][ogr][j]));
        x_out[(size_t)s * HD + t] = v;
    }
}

extern "C" void kernel_launch(void* const* d_in, const int* in_sizes, int n_in,
                              void* d_out, int out_size, void* d_ws, size_t ws_size,
                              hipStream_t stream) {
    const float* x   = (const float*)d_in[0];
    const float* pos = (const float*)d_in[1];
    const float* W1  = (const float*)d_in[2];
    const float* b1  = (const float*)d_in[3];
    const float* W2  = (const float*)d_in[4];
    const float* b2  = (const float*)d_in[5];

    float* out = (float*)d_out;
    float* x_out     = out;                                  // [8192,128]
    float* pos_out   = out + (size_t)NB * N_SAMPLE * HD;     // [8192,3]
    float* batch_out = pos_out + (size_t)NB * N_SAMPLE * 3;  // [8192]

    int*   idx_ws = (int*)d_ws;                              // 8192 ints
    float* g      = (float*)((char*)d_ws + 65536);           // [32768,128] f32

    fps_g_kernel<<<NB + (NB * N_PER) / 2, 256, 0, stream>>>(pos, x, W1, b1, g,
                                                            idx_ws, pos_out, batch_out);
    main_kernel<<<NB * N_SAMPLE, 256, 0, stream>>>(pos, W1, W2, b2, g, idx_ws, x_out);
}

// Round 4
// 1118.116 us; speedup vs baseline: 1.7863x; 1.0754x over previous
//
#include <hip/hip_runtime.h>

#define NB 8
#define N_PER 4096
#define N_SAMPLE 1024
#define KNN 64
#define CIN 64
#define HD 128
#define R2F 0.04f
#define LIST_CAP 384

// ---- DPP wave64 max-reduce (pure VALU, no LDS latency) ---------------------
template <int CTRL>
__device__ __forceinline__ unsigned dpp_max_step(unsigned v) {
    // old=0 => lanes with invalid source contribute identity 0 (all values >= 0)
    unsigned o = (unsigned)__builtin_amdgcn_update_dpp(0, (int)v, CTRL, 0xf, 0xf, false);
    return v > o ? v : o;
}
__device__ __forceinline__ unsigned wave_max_bcast(unsigned v) {
    v = dpp_max_step<0x111>(v);  // row_shr:1
    v = dpp_max_step<0x112>(v);  // row_shr:2
    v = dpp_max_step<0x114>(v);  // row_shr:4
    v = dpp_max_step<0x118>(v);  // row_shr:8
    v = dpp_max_step<0x142>(v);  // row_bcast:15
    v = dpp_max_step<0x143>(v);  // row_bcast:31 -> lane 63 has wave max
    return (unsigned)__builtin_amdgcn_readlane((int)v, 63);
}

// ---- combined FPS (blocks 0..7) + g precompute (blocks 8..) ----------------
// g = x@W1[:64] + pos@W1[64:67] + b1  (per-point part of layer 1)
__global__ __launch_bounds__(256) void fps_g_kernel(const float* __restrict__ pos,
                                                    const float* __restrict__ x,
                                                    const float* __restrict__ W1,
                                                    const float* __restrict__ b1,
                                                    float* __restrict__ g,
                                                    int* __restrict__ idx_out,
                                                    float* __restrict__ pos_out,
                                                    float* __restrict__ batch_out) {
    __shared__ float pxyz[N_PER * 3];  // interleaved x,y,z
    __shared__ unsigned long long pkey[2][4];
    const int t = threadIdx.x;

    if (blockIdx.x >= NB) {
        // ---------------- g part: 2 points per block ----------------
        const int n0 = (int)(blockIdx.x - NB) * 2;
        if (t < 2 * CIN) pxyz[t] = x[(size_t)n0 * CIN + t];
        if (t < 6) pxyz[512 + t] = pos[(size_t)n0 * 3 + t];
        __syncthreads();
        const int lp = t >> 7;
        const int h = t & 127;
        float acc = b1[h];
        const float* xv = pxyz + lp * CIN;
#pragma unroll 8
        for (int c = 0; c < CIN; ++c) acc += xv[c] * W1[c * HD + h];
        const float* pv = pxyz + 512 + lp * 3;
#pragma unroll
        for (int d = 0; d < 3; ++d) acc += pv[d] * W1[(CIN + d) * HD + h];
        g[(size_t)(n0 + lp) * HD + h] = acc;
        return;
    }

    // ---------------- FPS part: one block per cloud ----------------
    const int b = blockIdx.x;
    const float* posb = pos + (size_t)b * N_PER * 3;
    for (int i = t; i < N_PER * 3; i += 256) pxyz[i] = posb[i];
    for (int i = t; i < N_SAMPLE; i += 256) batch_out[b * N_SAMPLE + i] = (float)b;
    __syncthreads();

    // registers hold this thread's 16 points
    float rx[16], ry[16], rz[16], mind[16];
#pragma unroll
    for (int k = 0; k < 16; ++k) {
        const int p = t + (k << 8);
        rx[k] = pxyz[p * 3 + 0];
        ry[k] = pxyz[p * 3 + 1];
        rz[k] = pxyz[p * 3 + 2];
        mind[k] = 1e10f;
    }
    int last = 0;
    if (t == 0) {
        idx_out[b * N_SAMPLE] = b * N_PER;
        pos_out[(size_t)(b * N_SAMPLE) * 3 + 0] = pxyz[0];
        pos_out[(size_t)(b * N_SAMPLE) * 3 + 1] = pxyz[1];
        pos_out[(size_t)(b * N_SAMPLE) * 3 + 2] = pxyz[2];
    }

    for (int s = 1; s < N_SAMPLE; ++s) {
        const float* lp3 = pxyz + last * 3;  // broadcast read (same addr all lanes)
        const float lx = lp3[0], ly = lp3[1], lz = lp3[2];
        float bv = -1.0f;
        int bi = 0x7fffffff;
#pragma unroll
        for (int k = 0; k < 16; ++k) {
            const float dx = rx[k] - lx;
            const float dy = ry[k] - ly;
            const float dz = rz[k] - lz;
            // exact f32 left-to-right: (dx*dx + dy*dy) + dz*dz, no FMA contraction
            const float d = __fadd_rn(__fadd_rn(__fmul_rn(dx, dx), __fmul_rn(dy, dy)),
                                      __fmul_rn(dz, dz));
            const float m = fminf(mind[k], d);
            mind[k] = m;
            if (m > bv) { bv = m; bi = t + (k << 8); }  // strict > keeps lowest index
        }
        // wave argmax: dists >= 0 so f32 order == u32 order. DPP max, then among
        // lanes holding the max, max of ~bi == min index (exact tie-break).
        const unsigned bvu = __float_as_uint(bv);
        const unsigned maxu = wave_max_bcast(bvu);
        const unsigned cand = (bvu == maxu) ? ~(unsigned)bi : 0u;
        const unsigned wnbi = wave_max_bcast(cand);
        const unsigned long long key = ((unsigned long long)maxu << 32) | wnbi;

        const int par = s & 1;
        if ((t & 63) == 0) pkey[par][t >> 6] = key;
        __syncthreads();
        unsigned long long fk = pkey[par][0];
#pragma unroll
        for (int w = 1; w < 4; ++w) {
            const unsigned long long ok = pkey[par][w];
            fk = (ok > fk) ? ok : fk;
        }
        last = (int)(~(unsigned)fk);
        if (t == 0) {
            idx_out[b * N_SAMPLE + s] = b * N_PER + last;
            pos_out[(size_t)(b * N_SAMPLE + s) * 3 + 0] = pxyz[last * 3 + 0];
            pos_out[(size_t)(b * N_SAMPLE + s) * 3 + 1] = pxyz[last * 3 + 1];
            pos_out[(size_t)(b * N_SAMPLE + s) * 3 + 2] = pxyz[last * 3 + 2];
        }
        // parity ping-pong on pkey avoids a trailing barrier
    }
}

// ---- main: ball-query select + h1 + layer2 GEMM + masked max ---------------
__global__ __launch_bounds__(256) void main_kernel(const float* __restrict__ pos,
                                                   const float* __restrict__ W1,
                                                   const float* __restrict__ W2,
                                                   const float* __restrict__ b2,
                                                   const float* __restrict__ g,
                                                   const int* __restrict__ idx_in,
                                                   float* __restrict__ x_out) {
    __shared__ float h1[KNN][HD + 4];  // stride 132; readers use m = mg+16i (2-way max)
    __shared__ unsigned long long keys[LIST_CAP];
    __shared__ int sel[KNN];
    __shared__ float pcW[HD];
    __shared__ float cp[3];
    __shared__ int cnt;
    __shared__ float partial[4][16][8];

    const int t = threadIdx.x;
    const int s = blockIdx.x;
    const int b = s >> 10;
    const int gci = idx_in[s];
    if (t < 3) cp[t] = pos[(size_t)gci * 3 + t];
    if (t == 0) cnt = 0;
    __syncthreads();

    if (t < HD) {
        pcW[t] = cp[0] * W1[CIN * HD + t] + cp[1] * W1[(CIN + 1) * HD + t] +
                 cp[2] * W1[(CIN + 2) * HD + t];
    }

    const float cx = cp[0], cy = cp[1], cz = cp[2];
    const size_t base = (size_t)b * N_PER;
    const int lane = t & 63;
#pragma unroll
    for (int k = 0; k < 16; ++k) {
        const int p = t + (k << 8);
        const float* pp = pos + (base + p) * 3;
        const float dx = pp[0] - cx;
        const float dy = pp[1] - cy;
        const float dz = pp[2] - cz;
        const float d2 = __fadd_rn(__fadd_rn(__fmul_rn(dx, dx), __fmul_rn(dy, dy)),
                                   __fmul_rn(dz, dz));
        const bool hit = (d2 <= R2F);
        const unsigned long long m = __ballot(hit);
        if (m) {
            const int leader = __ffsll((unsigned long long)m) - 1;
            int wb = 0;
            if (lane == leader) wb = atomicAdd(&cnt, __popcll(m));
            wb = __shfl(wb, leader);
            if (hit) {
                const int slot = wb + __popcll(m & ((1ull << lane) - 1));
                if (slot < LIST_CAP)
                    keys[slot] =
                        ((unsigned long long)__float_as_uint(d2) << 32) | (unsigned)p;
            }
        }
    }
    __syncthreads();
    const int C = min(cnt, LIST_CAP);
    const int M = min(C, KNN);

    // exact top-K by rank of (d2, idx) key (matches lax.top_k tie semantics)
    for (int e = t; e < C; e += 256) {
        const unsigned long long ke = keys[e];
        int rank = 0;
        for (int q = 0; q < C; ++q) rank += (keys[q] < ke) ? 1 : 0;
        if (rank < KNN) sel[rank] = (int)(ke & 0xFFFFFFFFull);
    }
    __syncthreads();

    // h1[m][h] = relu(g[j_m][h] - pcW[h]); zero for invalid rows
    for (int lin = t; lin < KNN * HD; lin += 256) {
        const int m = lin >> 7;
        const int h = lin & 127;
        float v = 0.0f;
        if (m < M) v = fmaxf(g[(base + sel[m]) * HD + h] - pcW[h], 0.0f);
        h1[m][h] = v;
    }
    __syncthreads();

    // layer 2: [64x128] @ [128x128]; thread tile 4m x 8o, rows m = mg + 16*i
    // W2 read directly from global (L1/L2 broadcast) -> no staging barriers
    const int og = t & 15;
    const int mg = t >> 4;
    float acc[4][8];
#pragma unroll
    for (int i = 0; i < 4; ++i)
#pragma unroll
        for (int j = 0; j < 8; ++j) acc[i][j] = 0.0f;

    for (int h0 = 0; h0 < HD; h0 += 16) {
#pragma unroll
        for (int hh = 0; hh < 16; hh += 4) {
            float a4[4][4];
#pragma unroll
            for (int i = 0; i < 4; ++i) {
                const float4 v = *(const float4*)(&h1[mg + 16 * i][h0 + hh]);
                a4[i][0] = v.x; a4[i][1] = v.y; a4[i][2] = v.z; a4[i][3] = v.w;
            }
#pragma unroll
            for (int hp = 0; hp < 4; ++hp) {
                const int row = h0 + hh + hp;
                const float4 w0 = *(const float4*)(W2 + (size_t)row * HD + og * 8);
                const float4 w1 = *(const float4*)(W2 + (size_t)row * HD + og * 8 + 4);
                const float w[8] = {w0.x, w0.y, w0.z, w0.w, w1.x, w1.y, w1.z, w1.w};
#pragma unroll
                for (int i = 0; i < 4; ++i)
#pragma unroll
                    for (int j = 0; j < 8; ++j) acc[i][j] += a4[i][hp] * w[j];
            }
        }
    }

    // + b2, relu, mask invalid rows, max over m
    const float4 bA = *(const float4*)(b2 + og * 8);
    const float4 bB = *(const float4*)(b2 + og * 8 + 4);
    const float b2r[8] = {bA.x, bA.y, bA.z, bA.w, bB.x, bB.y, bB.z, bB.w};
    float mx[8];
#pragma unroll
    for (int j = 0; j < 8; ++j) mx[j] = -1e9f;
#pragma unroll
    for (int i = 0; i < 4; ++i) {
        const int m = mg + 16 * i;
        if (m < M) {
#pragma unroll
            for (int j = 0; j < 8; ++j) {
                const float v = fmaxf(acc[i][j] + b2r[j], 0.0f);
                mx[j] = fmaxf(mx[j], v);
            }
        }
    }
#pragma unroll
    for (int j = 0; j < 8; ++j) {
        mx[j] = fmaxf(mx[j], __shfl_xor(mx[j], 16));
        mx[j] = fmaxf(mx[j], __shfl_xor(mx[j], 32));
    }
    const int wv = t >> 6;
    if ((t & 63) < 16) {
#pragma unroll
        for (int j = 0; j < 8; ++j) partial[wv][t & 15][j] = mx[j];
    }
    __syncthreads();
    if (t < HD) {
        const int ogr = t >> 3, j = t & 7;
        const float v = fmaxf(fmaxf(partial[0][ogr][j], partial[1][ogr][j]),
                              fmaxf(partial[2][ogr][j], partial[3][ogr][j]));
        x_out[(size_t)s * HD + t] = v;
    }
}

extern "C" void kernel_launch(void* const* d_in, const int* in_sizes, int n_in,
                              void* d_out, int out_size, void* d_ws, size_t ws_size,
                              hipStream_t stream) {
    const float* x   = (const float*)d_in[0];
    const float* pos = (const float*)d_in[1];
    const float* W1  = (const float*)d_in[2];
    const float* b1  = (const float*)d_in[3];
    const float* W2  = (const float*)d_in[4];
    const float* b2  = (const float*)d_in[5];

    float* out = (float*)d_out;
    float* x_out     = out;                                  // [8192,128]
    float* pos_out   = out + (size_t)NB * N_SAMPLE * HD;     // [8192,3]
    float* batch_out = pos_out + (size_t)NB * N_SAMPLE * 3;  // [8192]

    int*   idx_ws = (int*)d_ws;                              // 8192 ints
    float* g      = (float*)((char*)d_ws + 65536);           // [32768,128] f32

    fps_g_kernel<<<NB + (NB * N_PER) / 2, 256, 0, stream>>>(pos, x, W1, b1, g,
                                                            idx_ws, pos_out, batch_out);
    main_kernel<<<NB * N_SAMPLE, 256, 0, stream>>>(pos, W1, W2, b2, g, idx_ws, x_out);
}

// Round 5
// 1109.146 us; speedup vs baseline: 1.8008x; 1.0081x over previous
//
#include <hip/hip_runtime.h>

#define NB 8
#define N_PER 4096
#define N_SAMPLE 1024
#define KNN 64
#define CIN 64
#define HD 128
#define R2F 0.04f
#define LIST_CAP 384

// ---- DPP wave64 64-bit max-reduce (pure VALU; lane 63 ends with the max) ---
template <int CTRL>
__device__ __forceinline__ unsigned long long dpp_shift_u64(unsigned long long k) {
    const unsigned lo = (unsigned)k;
    const unsigned hi = (unsigned)(k >> 32);
    // old=0, bound_ctrl=false: invalid-source lanes contribute identity 0
    const unsigned olo =
        (unsigned)__builtin_amdgcn_update_dpp(0, (int)lo, CTRL, 0xf, 0xf, false);
    const unsigned ohi =
        (unsigned)__builtin_amdgcn_update_dpp(0, (int)hi, CTRL, 0xf, 0xf, false);
    return ((unsigned long long)ohi << 32) | olo;
}
__device__ __forceinline__ unsigned long long wave_max_u64(unsigned long long k) {
    unsigned long long o;
    o = dpp_shift_u64<0x111>(k); k = o > k ? o : k;  // row_shr:1
    o = dpp_shift_u64<0x112>(k); k = o > k ? o : k;  // row_shr:2
    o = dpp_shift_u64<0x114>(k); k = o > k ? o : k;  // row_shr:4
    o = dpp_shift_u64<0x118>(k); k = o > k ? o : k;  // row_shr:8
    o = dpp_shift_u64<0x142>(k); k = o > k ? o : k;  // row_bcast:15
    o = dpp_shift_u64<0x143>(k); k = o > k ? o : k;  // row_bcast:31
    return k;                                        // lane 63 holds wave max
}

// ---- combined FPS (blocks 0..7) + g precompute (blocks 8..) ----------------
// g = x@W1[:64] + pos@W1[64:67] + b1  (per-point part of layer 1)
__global__ __launch_bounds__(256) void fps_g_kernel(const float* __restrict__ pos,
                                                    const float* __restrict__ x,
                                                    const float* __restrict__ W1,
                                                    const float* __restrict__ b1,
                                                    float* __restrict__ g,
                                                    int* __restrict__ idx_out,
                                                    float* __restrict__ pos_out,
                                                    float* __restrict__ batch_out) {
    __shared__ float pxyz[N_PER * 3];  // interleaved x,y,z
    __shared__ __align__(16) unsigned long long pkey[2][4];
    __shared__ int lhist[N_SAMPLE];
    const int t = threadIdx.x;

    if (blockIdx.x >= NB) {
        // ---------------- g part: 2 points per block ----------------
        const int n0 = (int)(blockIdx.x - NB) * 2;
        if (t < 2 * CIN) pxyz[t] = x[(size_t)n0 * CIN + t];
        if (t < 6) pxyz[512 + t] = pos[(size_t)n0 * 3 + t];
        __syncthreads();
        const int lp = t >> 7;
        const int h = t & 127;
        float acc = b1[h];
        const float* xv = pxyz + lp * CIN;
#pragma unroll 8
        for (int c = 0; c < CIN; ++c) acc += xv[c] * W1[c * HD + h];
        const float* pv = pxyz + 512 + lp * 3;
#pragma unroll
        for (int d = 0; d < 3; ++d) acc += pv[d] * W1[(CIN + d) * HD + h];
        g[(size_t)(n0 + lp) * HD + h] = acc;
        return;
    }

    // ---------------- FPS part: one block per cloud ----------------
    const int b = blockIdx.x;
    const float* posb = pos + (size_t)b * N_PER * 3;
    for (int i = t; i < N_PER * 3; i += 256) pxyz[i] = posb[i];
    if (t == 0) lhist[0] = 0;
    __syncthreads();

    // registers hold this thread's 16 points
    float rx[16], ry[16], rz[16], mind[16];
#pragma unroll
    for (int k = 0; k < 16; ++k) {
        const int p = t + (k << 8);
        rx[k] = pxyz[p * 3 + 0];
        ry[k] = pxyz[p * 3 + 1];
        rz[k] = pxyz[p * 3 + 2];
        mind[k] = 1e10f;
    }
    int last = 0;

    // NO global memory traffic inside this loop: the pre-barrier waitcnt then
    // only drains short DS ops (the in-loop global stores were costing
    // ~500 cyc/step of vmcnt-drain before s_barrier).
    for (int s = 1; s < N_SAMPLE; ++s) {
        const float* lp3 = pxyz + last * 3;  // broadcast read (same addr all lanes)
        const float lx = lp3[0], ly = lp3[1], lz = lp3[2];
        float bv = -1.0f;
        int bi = 0x7fffffff;
#pragma unroll
        for (int k = 0; k < 16; ++k) {
            const float dx = rx[k] - lx;
            const float dy = ry[k] - ly;
            const float dz = rz[k] - lz;
            // exact f32 left-to-right: (dx*dx + dy*dy) + dz*dz, no FMA contraction
            const float d = __fadd_rn(__fadd_rn(__fmul_rn(dx, dx), __fmul_rn(dy, dy)),
                                      __fmul_rn(dz, dz));
            const float m = fminf(mind[k], d);
            mind[k] = m;
            if (m > bv) { bv = m; bi = t + (k << 8); }  // strict > keeps lowest index
        }
        // wave argmax: dists >= 0 so (f32 dist, min idx) order == u64 order of
        // (dist_bits, ~idx). Single fused 64-bit DPP max-reduce; exact tie-break.
        unsigned long long key =
            ((unsigned long long)__float_as_uint(bv) << 32) | (unsigned)(~bi);
        key = wave_max_u64(key);

        const int par = s & 1;
        if ((t & 63) == 63) pkey[par][t >> 6] = key;  // lane 63 writes directly
        __syncthreads();
        const ulonglong2* pk2 = (const ulonglong2*)(&pkey[par][0]);
        const ulonglong2 A = pk2[0], Bq = pk2[1];
        unsigned long long f0 = A.x > A.y ? A.x : A.y;
        const unsigned long long f1 = Bq.x > Bq.y ? Bq.x : Bq.y;
        f0 = f0 > f1 ? f0 : f1;
        last = (int)(~(unsigned)f0);
        if (t == (s & 255)) lhist[s] = last;
        // parity ping-pong on pkey avoids a trailing barrier
    }
    __syncthreads();

    // tail: emit idx/pos/batch outputs in parallel (off the critical path)
    for (int i = t; i < N_SAMPLE; i += 256) {
        const int li = lhist[i];
        idx_out[b * N_SAMPLE + i] = b * N_PER + li;
        pos_out[(size_t)(b * N_SAMPLE + i) * 3 + 0] = pxyz[li * 3 + 0];
        pos_out[(size_t)(b * N_SAMPLE + i) * 3 + 1] = pxyz[li * 3 + 1];
        pos_out[(size_t)(b * N_SAMPLE + i) * 3 + 2] = pxyz[li * 3 + 2];
        batch_out[b * N_SAMPLE + i] = (float)b;
    }
}

// ---- main: ball-query select + h1 + layer2 GEMM + masked max ---------------
__global__ __launch_bounds__(256) void main_kernel(const float* __restrict__ pos,
                                                   const float* __restrict__ W1,
                                                   const float* __restrict__ W2,
                                                   const float* __restrict__ b2,
                                                   const float* __restrict__ g,
                                                   const int* __restrict__ idx_in,
                                                   float* __restrict__ x_out) {
    __shared__ float h1[KNN][HD + 4];  // stride 132; readers use m = mg+16i (2-way max)
    __shared__ unsigned long long keys[LIST_CAP];
    __shared__ int sel[KNN];
    __shared__ float pcW[HD];
    __shared__ float cp[3];
    __shared__ int cnt;
    __shared__ float partial[4][16][8];

    const int t = threadIdx.x;
    const int s = blockIdx.x;
    const int b = s >> 10;
    const int gci = idx_in[s];
    if (t < 3) cp[t] = pos[(size_t)gci * 3 + t];
    if (t == 0) cnt = 0;
    __syncthreads();

    if (t < HD) {
        pcW[t] = cp[0] * W1[CIN * HD + t] + cp[1] * W1[(CIN + 1) * HD + t] +
                 cp[2] * W1[(CIN + 2) * HD + t];
    }

    const float cx = cp[0], cy = cp[1], cz = cp[2];
    const size_t base = (size_t)b * N_PER;
    const int lane = t & 63;
#pragma unroll
    for (int k = 0; k < 16; ++k) {
        const int p = t + (k << 8);
        const float* pp = pos + (base + p) * 3;
        const float dx = pp[0] - cx;
        const float dy = pp[1] - cy;
        const float dz = pp[2] - cz;
        const float d2 = __fadd_rn(__fadd_rn(__fmul_rn(dx, dx), __fmul_rn(dy, dy)),
                                   __fmul_rn(dz, dz));
        const bool hit = (d2 <= R2F);
        const unsigned long long m = __ballot(hit);
        if (m) {
            const int leader = __ffsll((unsigned long long)m) - 1;
            int wb = 0;
            if (lane == leader) wb = atomicAdd(&cnt, __popcll(m));
            wb = __shfl(wb, leader);
            if (hit) {
                const int slot = wb + __popcll(m & ((1ull << lane) - 1));
                if (slot < LIST_CAP)
                    keys[slot] =
                        ((unsigned long long)__float_as_uint(d2) << 32) | (unsigned)p;
            }
        }
    }
    __syncthreads();
    const int C = min(cnt, LIST_CAP);
    const int M = min(C, KNN);

    // exact top-K by rank of (d2, idx) key (matches lax.top_k tie semantics)
    for (int e = t; e < C; e += 256) {
        const unsigned long long ke = keys[e];
        int rank = 0;
        for (int q = 0; q < C; ++q) rank += (keys[q] < ke) ? 1 : 0;
        if (rank < KNN) sel[rank] = (int)(ke & 0xFFFFFFFFull);
    }
    __syncthreads();

    // h1[m][h] = relu(g[j_m][h] - pcW[h]); zero for invalid rows
    for (int lin = t; lin < KNN * HD; lin += 256) {
        const int m = lin >> 7;
        const int h = lin & 127;
        float v = 0.0f;
        if (m < M) v = fmaxf(g[(base + sel[m]) * HD + h] - pcW[h], 0.0f);
        h1[m][h] = v;
    }
    __syncthreads();

    // layer 2: [64x128] @ [128x128]; thread tile 4m x 8o, rows m = mg + 16*i
    // W2 read directly from global (L1/L2 broadcast) -> no staging barriers
    const int og = t & 15;
    const int mg = t >> 4;
    float acc[4][8];
#pragma unroll
    for (int i = 0; i < 4; ++i)
#pragma unroll
        for (int j = 0; j < 8; ++j) acc[i][j] = 0.0f;

    for (int h0 = 0; h0 < HD; h0 += 16) {
#pragma unroll
        for (int hh = 0; hh < 16; hh += 4) {
            float a4[4][4];
#pragma unroll
            for (int i = 0; i < 4; ++i) {
                const float4 v = *(const float4*)(&h1[mg + 16 * i][h0 + hh]);
                a4[i][0] = v.x; a4[i][1] = v.y; a4[i][2] = v.z; a4[i][3] = v.w;
            }
#pragma unroll
            for (int hp = 0; hp < 4; ++hp) {
                const int row = h0 + hh + hp;
                const float4 w0 = *(const float4*)(W2 + (size_t)row * HD + og * 8);
                const float4 w1 = *(const float4*)(W2 + (size_t)row * HD + og * 8 + 4);
                const float w[8] = {w0.x, w0.y, w0.z, w0.w, w1.x, w1.y, w1.z, w1.w};
#pragma unroll
                for (int i = 0; i < 4; ++i)
#pragma unroll
                    for (int j = 0; j < 8; ++j) acc[i][j] += a4[i][hp] * w[j];
            }
        }
    }

    // + b2, relu, mask invalid rows, max over m
    const float4 bA = *(const float4*)(b2 + og * 8);
    const float4 bB = *(const float4*)(b2 + og * 8 + 4);
    const float b2r[8] = {bA.x, bA.y, bA.z, bA.w, bB.x, bB.y, bB.z, bB.w};
    float mx[8];
#pragma unroll
    for (int j = 0; j < 8; ++j) mx[j] = -1e9f;
#pragma unroll
    for (int i = 0; i < 4; ++i) {
        const int m = mg + 16 * i;
        if (m < M) {
#pragma unroll
            for (int j = 0; j < 8; ++j) {
                const float v = fmaxf(acc[i][j] + b2r[j], 0.0f);
                mx[j] = fmaxf(mx[j], v);
            }
        }
    }
#pragma unroll
    for (int j = 0; j < 8; ++j) {
        mx[j] = fmaxf(mx[j], __shfl_xor(mx[j], 16));
        mx[j] = fmaxf(mx[j], __shfl_xor(mx[j], 32));
    }
    const int wv = t >> 6;
    if ((t & 63) < 16) {
#pragma unroll
        for (int j = 0; j < 8; ++j) partial[wv][t & 15][j] = mx[j];
    }
    __syncthreads();
    if (t < HD) {
        const int ogr = t >> 3, j = t & 7;
        const float v = fmaxf(fmaxf(partial[0][ogr][j], partial[1][ogr][j]),
                              fmaxf(partial[2][ogr][j], partial[3][ogr][j]));
        x_out[(size_t)s * HD + t] = v;
    }
}

extern "C" void kernel_launch(void* const* d_in, const int* in_sizes, int n_in,
                              void* d_out, int out_size, void* d_ws, size_t ws_size,
                              hipStream_t stream) {
    const float* x   = (const float*)d_in[0];
    const float* pos = (const float*)d_in[1];
    const float* W1  = (const float*)d_in[2];
    const float* b1  = (const float*)d_in[3];
    const float* W2  = (const float*)d_in[4];
    const float* b2  = (const float*)d_in[5];

    float* out = (float*)d_out;
    float* x_out     = out;                                  // [8192,128]
    float* pos_out   = out + (size_t)NB * N_SAMPLE * HD;     // [8192,3]
    float* batch_out = pos_out + (size_t)NB * N_SAMPLE * 3;  // [8192]

    int*   idx_ws = (int*)d_ws;                              // 8192 ints
    float* g      = (float*)((char*)d_ws + 65536);           // [32768,128] f32

    fps_g_kernel<<<NB + (NB * N_PER) / 2, 256, 0, stream>>>(pos, x, W1, b1, g,
                                                            idx_ws, pos_out, batch_out);
    main_kernel<<<NB * N_SAMPLE, 256, 0, stream>>>(pos, W1, W2, b2, g, idx_ws, x_out);
}

// Round 6
// 862.892 us; speedup vs baseline: 2.3147x; 1.2854x over previous
//
#include <hip/hip_runtime.h>

#define NB 8
#define N_PER 4096
#define N_SAMPLE 1024
#define KNN 64
#define CIN 64
#define HD 128
#define R2F 0.04f
#define LIST_CAP 384
#define STR 136  // h1 bf16 LDS row stride (shorts); 136*2=272B, 16B-aligned

typedef __attribute__((ext_vector_type(8))) short bf16x8;
typedef __attribute__((ext_vector_type(4))) float f32x4;

__device__ __forceinline__ unsigned short f2bf(float f) {
    const unsigned u = __float_as_uint(f);
    return (unsigned short)((u + 0x7fff + ((u >> 16) & 1)) >> 16);  // RNE
}

// ---- DPP wave64 64-bit max-reduce (pure VALU; lane 63 ends with the max) ---
template <int CTRL>
__device__ __forceinline__ unsigned long long dpp_shift_u64(unsigned long long k) {
    const unsigned lo = (unsigned)k;
    const unsigned hi = (unsigned)(k >> 32);
    const unsigned olo =
        (unsigned)__builtin_amdgcn_update_dpp(0, (int)lo, CTRL, 0xf, 0xf, false);
    const unsigned ohi =
        (unsigned)__builtin_amdgcn_update_dpp(0, (int)hi, CTRL, 0xf, 0xf, false);
    return ((unsigned long long)ohi << 32) | olo;
}
__device__ __forceinline__ unsigned long long wave_max_u64(unsigned long long k) {
    unsigned long long o;
    o = dpp_shift_u64<0x111>(k); k = o > k ? o : k;  // row_shr:1
    o = dpp_shift_u64<0x112>(k); k = o > k ? o : k;  // row_shr:2
    o = dpp_shift_u64<0x114>(k); k = o > k ? o : k;  // row_shr:4
    o = dpp_shift_u64<0x118>(k); k = o > k ? o : k;  // row_shr:8
    o = dpp_shift_u64<0x142>(k); k = o > k ? o : k;  // row_bcast:15
    o = dpp_shift_u64<0x143>(k); k = o > k ? o : k;  // row_bcast:31
    return k;                                        // lane 63 holds wave max
}

// ---- FPS (blocks 0..7) + g precompute + W2T bf16 transpose -----------------
// g = x@W1[:64] + pos@W1[64:67] + b1  (per-point part of layer 1)
// W2T[n*128+k] = bf16(W2[k*128+n])  (B-operand-friendly layout)
#define GBLOCKS ((NB * N_PER) / 2)
__global__ __launch_bounds__(256) void fps_g_kernel(const float* __restrict__ pos,
                                                    const float* __restrict__ x,
                                                    const float* __restrict__ W1,
                                                    const float* __restrict__ b1,
                                                    const float* __restrict__ W2,
                                                    float* __restrict__ g,
                                                    short* __restrict__ w2t,
                                                    int* __restrict__ idx_out,
                                                    float* __restrict__ pos_out,
                                                    float* __restrict__ batch_out) {
    __shared__ float pxyz[N_PER * 3];  // interleaved x,y,z
    __shared__ __align__(16) unsigned long long pkey[2][4];
    __shared__ int lhist[N_SAMPLE];
    const int t = threadIdx.x;

    if (blockIdx.x >= NB + GBLOCKS) {
        // ---------------- W2T part: 8 blocks, 8 elems/thread ----------------
        const int base = (int)(blockIdx.x - (NB + GBLOCKS)) * 2048 + t * 8;
#pragma unroll
        for (int i = 0; i < 8; ++i) {
            const int idx = base + i;  // = n*128 + k
            const int n = idx >> 7, k = idx & 127;
            w2t[idx] = (short)f2bf(W2[k * HD + n]);
        }
        return;
    }

    if (blockIdx.x >= NB) {
        // ---------------- g part: 2 points per block ----------------
        const int n0 = (int)(blockIdx.x - NB) * 2;
        if (t < 2 * CIN) pxyz[t] = x[(size_t)n0 * CIN + t];
        if (t < 6) pxyz[512 + t] = pos[(size_t)n0 * 3 + t];
        __syncthreads();
        const int lp = t >> 7;
        const int h = t & 127;
        float acc = b1[h];
        const float* xv = pxyz + lp * CIN;
#pragma unroll 8
        for (int c = 0; c < CIN; ++c) acc += xv[c] * W1[c * HD + h];
        const float* pv = pxyz + 512 + lp * 3;
#pragma unroll
        for (int d = 0; d < 3; ++d) acc += pv[d] * W1[(CIN + d) * HD + h];
        g[(size_t)(n0 + lp) * HD + h] = acc;
        return;
    }

    // ---------------- FPS part: one block per cloud ----------------
    const int b = blockIdx.x;
    const float* posb = pos + (size_t)b * N_PER * 3;
    for (int i = t; i < N_PER * 3; i += 256) pxyz[i] = posb[i];
    if (t == 0) lhist[0] = 0;
    __syncthreads();

    float rx[16], ry[16], rz[16], mind[16];
#pragma unroll
    for (int k = 0; k < 16; ++k) {
        const int p = t + (k << 8);
        rx[k] = pxyz[p * 3 + 0];
        ry[k] = pxyz[p * 3 + 1];
        rz[k] = pxyz[p * 3 + 2];
        mind[k] = 1e10f;
    }
    int last = 0;

    for (int s = 1; s < N_SAMPLE; ++s) {
        const float* lp3 = pxyz + last * 3;
        const float lx = lp3[0], ly = lp3[1], lz = lp3[2];
        float bv = -1.0f;
        int bi = 0x7fffffff;
#pragma unroll
        for (int k = 0; k < 16; ++k) {
            const float dx = rx[k] - lx;
            const float dy = ry[k] - ly;
            const float dz = rz[k] - lz;
            // exact f32 left-to-right: (dx*dx + dy*dy) + dz*dz, no FMA contraction
            const float d = __fadd_rn(__fadd_rn(__fmul_rn(dx, dx), __fmul_rn(dy, dy)),
                                      __fmul_rn(dz, dz));
            const float m = fminf(mind[k], d);
            mind[k] = m;
            if (m > bv) { bv = m; bi = t + (k << 8); }
        }
        // dists >= 0 so (f32 dist, min idx) order == u64 order of (dist_bits, ~idx)
        unsigned long long key =
            ((unsigned long long)__float_as_uint(bv) << 32) | (unsigned)(~bi);
        key = wave_max_u64(key);

        const int par = s & 1;
        if ((t & 63) == 63) pkey[par][t >> 6] = key;
        __syncthreads();
        const ulonglong2* pk2 = (const ulonglong2*)(&pkey[par][0]);
        const ulonglong2 A = pk2[0], Bq = pk2[1];
        unsigned long long f0 = A.x > A.y ? A.x : A.y;
        const unsigned long long f1 = Bq.x > Bq.y ? Bq.x : Bq.y;
        f0 = f0 > f1 ? f0 : f1;
        last = (int)(~(unsigned)f0);
        if (t == (s & 255)) lhist[s] = last;
    }
    __syncthreads();

    for (int i = t; i < N_SAMPLE; i += 256) {
        const int li = lhist[i];
        idx_out[b * N_SAMPLE + i] = b * N_PER + li;
        pos_out[(size_t)(b * N_SAMPLE + i) * 3 + 0] = pxyz[li * 3 + 0];
        pos_out[(size_t)(b * N_SAMPLE + i) * 3 + 1] = pxyz[li * 3 + 1];
        pos_out[(size_t)(b * N_SAMPLE + i) * 3 + 2] = pxyz[li * 3 + 2];
        batch_out[b * N_SAMPLE + i] = (float)b;
    }
}

// ---- main: ball-query select + bf16 h1 + MFMA layer-2 + masked max ---------
__global__ __launch_bounds__(256) void main_kernel(const float* __restrict__ pos,
                                                   const float* __restrict__ W1,
                                                   const short* __restrict__ W2T,
                                                   const float* __restrict__ b2,
                                                   const float* __restrict__ g,
                                                   const int* __restrict__ idx_in,
                                                   float* __restrict__ x_out) {
    __shared__ short h1b[KNN * STR];  // bf16 [64][STR]
    __shared__ unsigned long long keys[LIST_CAP];
    __shared__ int sel[KNN];
    __shared__ float pcW[HD];
    __shared__ float cp[3];
    __shared__ int cnt;
    __shared__ float stripmax[4][HD];

    const int t = threadIdx.x;
    const int s = blockIdx.x;
    const int b = s >> 10;
    const int gci = idx_in[s];
    if (t < 3) cp[t] = pos[(size_t)gci * 3 + t];
    if (t == 0) cnt = 0;
    __syncthreads();

    if (t < HD) {
        pcW[t] = cp[0] * W1[CIN * HD + t] + cp[1] * W1[(CIN + 1) * HD + t] +
                 cp[2] * W1[(CIN + 2) * HD + t];
    }

    const float cx = cp[0], cy = cp[1], cz = cp[2];
    const size_t base = (size_t)b * N_PER;
    const int lane = t & 63;
#pragma unroll
    for (int k = 0; k < 16; ++k) {
        const int p = t + (k << 8);
        const float* pp = pos + (base + p) * 3;
        const float dx = pp[0] - cx;
        const float dy = pp[1] - cy;
        const float dz = pp[2] - cz;
        const float d2 = __fadd_rn(__fadd_rn(__fmul_rn(dx, dx), __fmul_rn(dy, dy)),
                                   __fmul_rn(dz, dz));
        const bool hit = (d2 <= R2F);
        const unsigned long long m = __ballot(hit);
        if (m) {
            const int leader = __ffsll((unsigned long long)m) - 1;
            int wb = 0;
            if (lane == leader) wb = atomicAdd(&cnt, __popcll(m));
            wb = __shfl(wb, leader);
            if (hit) {
                const int slot = wb + __popcll(m & ((1ull << lane) - 1));
                if (slot < LIST_CAP)
                    keys[slot] =
                        ((unsigned long long)__float_as_uint(d2) << 32) | (unsigned)p;
            }
        }
    }
    __syncthreads();
    const int C = min(cnt, LIST_CAP);
    const int M = min(C, KNN);

    // exact top-K by rank of (d2, idx) key (matches lax.top_k tie semantics)
    for (int e = t; e < C; e += 256) {
        const unsigned long long ke = keys[e];
        int rank = 0;
        for (int q = 0; q < C; ++q) rank += (keys[q] < ke) ? 1 : 0;
        if (rank < KNN) sel[rank] = (int)(ke & 0xFFFFFFFFull);
    }
    __syncthreads();

    // h1[m][h] = relu(g[j_m][h] - pcW[h]) -> bf16 into LDS (zeros for m >= M)
    for (int lin = t; lin < KNN * (HD / 2); lin += 256) {
        const int m = lin >> 6;
        const int hp = lin & 63;  // handles h = 2hp, 2hp+1
        float v0 = 0.0f, v1 = 0.0f;
        if (m < M) {
            const float2 gv = *(const float2*)(g + (base + sel[m]) * HD + 2 * hp);
            v0 = fmaxf(gv.x - pcW[2 * hp], 0.0f);
            v1 = fmaxf(gv.y - pcW[2 * hp + 1], 0.0f);
        }
        const unsigned pk = (unsigned)f2bf(v0) | ((unsigned)f2bf(v1) << 16);
        *(unsigned*)(&h1b[m * STR + 2 * hp]) = pk;
    }
    __syncthreads();

    // layer 2 via MFMA 16x16x32 bf16. Wave w owns m-strip [16w,16w+16).
    // A[m=lane&15][k=quad*8+j] (m120-verified), C/D col=lane&15,row=quad*4+reg (m89).
    const int w = t >> 6;
    const int row = lane & 15;
    const int kg = lane >> 4;  // quad

    bf16x8 afr[4];
#pragma unroll
    for (int kc = 0; kc < 4; ++kc)
        afr[kc] = *(const bf16x8*)(&h1b[(w * 16 + row) * STR + kc * 32 + kg * 8]);

#pragma unroll
    for (int nt = 0; nt < 8; ++nt) {
        f32x4 acc = {0.0f, 0.0f, 0.0f, 0.0f};
#pragma unroll
        for (int kc = 0; kc < 4; ++kc) {
            const bf16x8 bfr =
                *(const bf16x8*)(W2T + (nt * 16 + row) * HD + kc * 32 + kg * 8);
            acc = __builtin_amdgcn_mfma_f32_16x16x32_bf16(afr[kc], bfr, acc, 0, 0, 0);
        }
        const float bb = b2[nt * 16 + row];
        float mxv = -1e9f;
#pragma unroll
        for (int r = 0; r < 4; ++r) {
            const int m = w * 16 + kg * 4 + r;
            const float v = fmaxf(acc[r] + bb, 0.0f);
            if (m < M) mxv = fmaxf(mxv, v);
        }
        mxv = fmaxf(mxv, __shfl_xor(mxv, 16));
        mxv = fmaxf(mxv, __shfl_xor(mxv, 32));
        if (lane < 16) stripmax[w][nt * 16 + lane] = mxv;
    }
    __syncthreads();
    if (t < HD) {
        const float v = fmaxf(fmaxf(stripmax[0][t], stripmax[1][t]),
                              fmaxf(stripmax[2][t], stripmax[3][t]));
        x_out[(size_t)s * HD + t] = v;
    }
}

extern "C" void kernel_launch(void* const* d_in, const int* in_sizes, int n_in,
                              void* d_out, int out_size, void* d_ws, size_t ws_size,
                              hipStream_t stream) {
    const float* x   = (const float*)d_in[0];
    const float* pos = (const float*)d_in[1];
    const float* W1  = (const float*)d_in[2];
    const float* b1  = (const float*)d_in[3];
    const float* W2  = (const float*)d_in[4];
    const float* b2  = (const float*)d_in[5];

    float* out = (float*)d_out;
    float* x_out     = out;                                  // [8192,128]
    float* pos_out   = out + (size_t)NB * N_SAMPLE * HD;     // [8192,3]
    float* batch_out = pos_out + (size_t)NB * N_SAMPLE * 3;  // [8192]

    int*   idx_ws = (int*)d_ws;                              // [0,32K): 8192 ints
    short* w2t    = (short*)((char*)d_ws + 32768);           // [32K,64K): bf16 W2T
    float* g      = (float*)((char*)d_ws + 65536);           // [64K,+16M): [32768,128] f32

    fps_g_kernel<<<NB + GBLOCKS + 8, 256, 0, stream>>>(pos, x, W1, b1, W2, g, w2t,
                                                       idx_ws, pos_out, batch_out);
    main_kernel<<<NB * N_SAMPLE, 256, 0, stream>>>(pos, W1, w2t, b2, g, idx_ws, x_out);
}